// Round 11
// baseline (171.365 us; speedup 1.0000x reference)
//
#include <hip/hip_runtime.h>
#include <cstdint>
#include <cstddef>

// Problem constants (from reference): B=2, T=2048, C=1024, H=16, hs=64
// Harness dtypes: inputs fp32, output fp32; internal compute bf16 MFMA.
#define BB 2
#define TT 2048
#define CC 1024
#define HH 16
#define HS 64
#define MM (BB*TT)      // 4096 rows
#define N1 (3*CC)       // 3072 qkv cols

// P-scratch row stride in elements (80 B/row)
#define PST2 40

// q prescale: hs^-0.5 * log2(e)  -> softmax_e(s) == softmax_2(s*log2e)
#define QSCALE 0.1803368801111243f

typedef __bf16 bf16_t;
typedef bf16_t bf16x8 __attribute__((ext_vector_type(8)));
typedef float  floatx4 __attribute__((ext_vector_type(4)));

__device__ __forceinline__ bf16_t f2bf(float f) {
    uint32_t u = __builtin_bit_cast(uint32_t, f);
    u += 0x7FFFu + ((u >> 16) & 1u);   // round-to-nearest-even
    unsigned short s = (unsigned short)(u >> 16);
    return __builtin_bit_cast(bf16_t, s);
}

__device__ __forceinline__ void load_lds16(const bf16_t* g, bf16_t* l) {
    __builtin_amdgcn_global_load_lds((__attribute__((address_space(1))) void*)g,
                                     (__attribute__((address_space(3))) void*)l,
                                     16, 0, 0);
}

// ---------------------------------------------------------------- prep (pack x + transpose both weights)
__device__ __forceinline__ void transpose_body(const float* __restrict__ src,
                                               bf16_t* __restrict__ dst,
                                               int R, int Ccol, int bx, int by,
                                               int tx, int ty, bf16_t (*tile)[33]) {
    int c0 = bx * 32, r0 = by * 32;
    for (int i = ty; i < 32; i += 8)
        tile[i][tx] = f2bf(src[(size_t)(r0 + i) * Ccol + c0 + tx]);
    __syncthreads();
    for (int i = ty; i < 32; i += 8)
        dst[(size_t)(c0 + i) * R + r0 + tx] = tile[tx][i];
}

__global__ __launch_bounds__(256) void k_prep(const float* __restrict__ x,
                                              const float* __restrict__ Wqkv,
                                              const float* __restrict__ Wout,
                                              bf16_t* __restrict__ xb,
                                              bf16_t* __restrict__ Wt1,
                                              bf16_t* __restrict__ Wt2) {
    __shared__ bf16_t tile[32][33];
    const int bid = blockIdx.x, tid = threadIdx.x;
    if (bid < 2048) {                       // pack x: 4M elems, 8/thread
        size_t i = ((size_t)bid * 256 + tid) * 8;
        float4 a = *(const float4*)(x + i);
        float4 b = *(const float4*)(x + i + 4);
        bf16x8 o;
        o[0] = f2bf(a.x); o[1] = f2bf(a.y); o[2] = f2bf(a.z); o[3] = f2bf(a.w);
        o[4] = f2bf(b.x); o[5] = f2bf(b.y); o[6] = f2bf(b.z); o[7] = f2bf(b.w);
        *(bf16x8*)(xb + i) = o;
    } else if (bid < 2048 + 3072) {         // Wqkv^T: grid (96,32)
        int bb = bid - 2048;
        transpose_body(Wqkv, Wt1, CC, N1, bb % 96, bb / 96, tid & 31, tid >> 5, tile);
    } else {                                // Wout^T: grid (32,32)
        int bb = bid - 5120;
        transpose_body(Wout, Wt2, CC, CC, bb & 31, bb >> 5, tid & 31, tid >> 5, tile);
    }
}

// ---------------------------------------------------------------- QKV GEMM: 256x256 tile, 192 blocks,
// 8 waves (2Mx4N), per-wave 128x64, acc[8][4]. BK=64 iterations, double-buffered
// LDS (128 KB), operands stored in STRIPE-ORDERED HALVES (A by mf-half rows,
// B by nf-half rows) staged in first-use order A-h0,B-h0,B-h1,A-h1 (2 uniform
// gload_lds/thread each). Only 3 barriers + 3 counted vmcnt gates per 64-MFMA
// iteration (4/3/2 steady; 4/2/0 last); 6 phases run barrier-free so the
// compiler schedules 48 MFMA || 16 ds_read || 6 gloads freely. XOR chunk
// swizzle (key = row&7) on both sides. NO sched_barrier / manual lgkmcnt
// (r2/r5 lessons). Epilogue = r1-verified q/k/sigma-v.
__global__ __launch_bounds__(512) void k_gemm_qkv(const bf16_t* __restrict__ x,
                                                  const bf16_t* __restrict__ Wt,
                                                  bf16_t* __restrict__ qb,
                                                  bf16_t* __restrict__ kb,
                                                  bf16_t* __restrict__ vt) {
    __shared__ bf16_t As[2][256 * 64];   // 32 KB per buffer
    __shared__ bf16_t Bs[2][256 * 64];   // 32 KB per buffer
    const int tid = threadIdx.x;
    const int wave = tid >> 6, lane = tid & 63;
    const int quad = lane >> 4, lrow = lane & 15;
    const int wm = wave >> 2, wn = wave & 3;

    // bijective XCD swizzle: 192 blocks (12x16), 24 contiguous tiles per XCD
    const int bid = blockIdx.y * 12 + blockIdx.x;
    const int swz = (bid & 7) * 24 + (bid >> 3);
    const int m0 = (swz / 12) * 256, n0 = (swz % 12) * 256;

    floatx4 acc[8][4];
    #pragma unroll
    for (int i = 0; i < 8; ++i)
        #pragma unroll
        for (int j = 0; j < 4; ++j) acc[i][j] = floatx4{0.f, 0.f, 0.f, 0.f};

    // ---- staging: one 512-chunk (16B) slab per call; LDS linear (gload_lds),
    // source pre-swizzled gc = cl ^ (rho&7). A stripe order: rho=[mfh][wm][rr6];
    // B stripe order: rho=[nfh][wn][rr5].
    auto stA = [&](int slot, int kk, int base) {
        int L = base + tid;
        int rho = L >> 3, cl = L & 7;
        int gc = cl ^ (rho & 7);
        int rg = ((rho >> 6) & 1) * 128 + (rho >> 7) * 64 + (rho & 63);
        load_lds16(x + (size_t)(m0 + rg) * CC + kk + gc * 8,
                   &As[slot][(size_t)L * 8]);
    };
    auto stB = [&](int slot, int kk, int base) {
        int L = base + tid;
        int rho = L >> 3, cl = L & 7;
        int gc = cl ^ (rho & 7);
        int rg = ((rho >> 5) & 3) * 64 + (rho >> 7) * 32 + (rho & 31);
        load_lds16(Wt + (size_t)(n0 + rg) * CC + kk + gc * 8,
                   &Bs[slot][(size_t)L * 8]);
    };

    // ---- reads: logical chunk c = ks*4+quad at swizzled slot c ^ (lrow&7)
    auto rdA = [&](int slot, int mfh, int mf_in, int ks) -> bf16x8 {
        int rho = mfh * 128 + wm * 64 + mf_in * 16 + lrow;
        int sw = ((ks * 4 + quad) ^ (lrow & 7)) * 8;
        return *(const bf16x8*)(&As[slot][rho * 64 + sw]);
    };
    auto rdB = [&](int slot, int nfh, int nf_in, int ks) -> bf16x8 {
        int rho = nfh * 128 + wn * 32 + nf_in * 16 + lrow;
        int sw = ((ks * 4 + quad) ^ (lrow & 7)) * 8;
        return *(const bf16x8*)(&Bs[slot][rho * 64 + sw]);
    };

    // prologue: stage iter 0 fully, in the steady-state issue order
    stA(0, 0, 0); stA(0, 0, 512);
    stB(0, 0, 0); stB(0, 0, 512);
    stB(0, 0, 1024); stB(0, 0, 1536);
    stA(0, 0, 1024); stA(0, 0, 1536);

    bf16x8 af[4], bf0[2], bf1[2];

    for (int kt = 0; kt < 16; ++kt) {
        const bool st = kt < 15;
        const int slot = kt & 1, sl2 = (kt + 1) & 1;
        const int kk2 = (kt + 1) * 64;

        // ===== gate 0: A-h0 & B-h0 of this iter landed (4 newer in flight) ==
        asm volatile("s_waitcnt vmcnt(4)" ::: "memory");
        __builtin_amdgcn_s_barrier();
        // phase 0: (mfh0, nfh0, ks0)
        #pragma unroll
        for (int i = 0; i < 4; ++i) af[i] = rdA(slot, 0, i, 0);
        bf0[0] = rdB(slot, 0, 0, 0); bf0[1] = rdB(slot, 0, 1, 0);
        if (st) stA(sl2, kk2, 0);
        __builtin_amdgcn_s_setprio(1);
        #pragma unroll
        for (int i = 0; i < 4; ++i) {
            acc[i][0] = __builtin_amdgcn_mfma_f32_16x16x32_bf16(af[i], bf0[0], acc[i][0], 0, 0, 0);
            acc[i][1] = __builtin_amdgcn_mfma_f32_16x16x32_bf16(af[i], bf0[1], acc[i][1], 0, 0, 0);
        }
        __builtin_amdgcn_s_setprio(0);

        // ===== gate 1: B-h1 landed ==========================================
        if (st) asm volatile("s_waitcnt vmcnt(3)" ::: "memory");
        else    asm volatile("s_waitcnt vmcnt(2)" ::: "memory");
        __builtin_amdgcn_s_barrier();
        // phase 1: (mfh0, nfh1, ks0)
        bf1[0] = rdB(slot, 1, 0, 0); bf1[1] = rdB(slot, 1, 1, 0);
        if (st) stA(sl2, kk2, 512);
        __builtin_amdgcn_s_setprio(1);
        #pragma unroll
        for (int i = 0; i < 4; ++i) {
            acc[i][2] = __builtin_amdgcn_mfma_f32_16x16x32_bf16(af[i], bf1[0], acc[i][2], 0, 0, 0);
            acc[i][3] = __builtin_amdgcn_mfma_f32_16x16x32_bf16(af[i], bf1[1], acc[i][3], 0, 0, 0);
        }
        __builtin_amdgcn_s_setprio(0);

        // ===== gate 2: A-h1 landed; phases 2-7 run barrier-free =============
        if (st) asm volatile("s_waitcnt vmcnt(2)" ::: "memory");
        else    asm volatile("s_waitcnt vmcnt(0)" ::: "memory");
        __builtin_amdgcn_s_barrier();
        __builtin_amdgcn_s_setprio(1);
        // phase 2: (mfh1, nfh0, ks0)
        #pragma unroll
        for (int i = 0; i < 4; ++i) af[i] = rdA(slot, 1, i, 0);
        if (st) stB(sl2, kk2, 0);
        #pragma unroll
        for (int i = 0; i < 4; ++i) {
            acc[4 + i][0] = __builtin_amdgcn_mfma_f32_16x16x32_bf16(af[i], bf0[0], acc[4 + i][0], 0, 0, 0);
            acc[4 + i][1] = __builtin_amdgcn_mfma_f32_16x16x32_bf16(af[i], bf0[1], acc[4 + i][1], 0, 0, 0);
        }
        // phase 3: (mfh1, nfh1, ks0)
        if (st) stB(sl2, kk2, 512);
        #pragma unroll
        for (int i = 0; i < 4; ++i) {
            acc[4 + i][2] = __builtin_amdgcn_mfma_f32_16x16x32_bf16(af[i], bf1[0], acc[4 + i][2], 0, 0, 0);
            acc[4 + i][3] = __builtin_amdgcn_mfma_f32_16x16x32_bf16(af[i], bf1[1], acc[4 + i][3], 0, 0, 0);
        }
        // phase 4: (mfh0, nfh0, ks1)
        #pragma unroll
        for (int i = 0; i < 4; ++i) af[i] = rdA(slot, 0, i, 1);
        bf0[0] = rdB(slot, 0, 0, 1); bf0[1] = rdB(slot, 0, 1, 1);
        if (st) stB(sl2, kk2, 1024);
        #pragma unroll
        for (int i = 0; i < 4; ++i) {
            acc[i][0] = __builtin_amdgcn_mfma_f32_16x16x32_bf16(af[i], bf0[0], acc[i][0], 0, 0, 0);
            acc[i][1] = __builtin_amdgcn_mfma_f32_16x16x32_bf16(af[i], bf0[1], acc[i][1], 0, 0, 0);
        }
        // phase 5: (mfh0, nfh1, ks1)
        bf1[0] = rdB(slot, 1, 0, 1); bf1[1] = rdB(slot, 1, 1, 1);
        if (st) stB(sl2, kk2, 1536);
        #pragma unroll
        for (int i = 0; i < 4; ++i) {
            acc[i][2] = __builtin_amdgcn_mfma_f32_16x16x32_bf16(af[i], bf1[0], acc[i][2], 0, 0, 0);
            acc[i][3] = __builtin_amdgcn_mfma_f32_16x16x32_bf16(af[i], bf1[1], acc[i][3], 0, 0, 0);
        }
        // phase 6: (mfh1, nfh0, ks1)
        #pragma unroll
        for (int i = 0; i < 4; ++i) af[i] = rdA(slot, 1, i, 1);
        if (st) stA(sl2, kk2, 1024);
        #pragma unroll
        for (int i = 0; i < 4; ++i) {
            acc[4 + i][0] = __builtin_amdgcn_mfma_f32_16x16x32_bf16(af[i], bf0[0], acc[4 + i][0], 0, 0, 0);
            acc[4 + i][1] = __builtin_amdgcn_mfma_f32_16x16x32_bf16(af[i], bf0[1], acc[4 + i][1], 0, 0, 0);
        }
        // phase 7: (mfh1, nfh1, ks1)
        if (st) stA(sl2, kk2, 1536);
        #pragma unroll
        for (int i = 0; i < 4; ++i) {
            acc[4 + i][2] = __builtin_amdgcn_mfma_f32_16x16x32_bf16(af[i], bf1[0], acc[4 + i][2], 0, 0, 0);
            acc[4 + i][3] = __builtin_amdgcn_mfma_f32_16x16x32_bf16(af[i], bf1[1], acc[4 + i][3], 0, 0, 0);
        }
        __builtin_amdgcn_s_setprio(0);
    }

    // ---- epilogue (r1-verified): q (prescaled), k natural, v sigma-packed
    const int b = m0 >> 11;                  // whole block in one batch row
    #pragma unroll
    for (int nf = 0; nf < 4; ++nf) {
        int gn = n0 + wn * 64 + nf * 16 + lrow;
        int which = gn >> 10, c = gn & 1023, h = c >> 6, d = c & 63;
        if (which == 0) {
            #pragma unroll
            for (int mf = 0; mf < 8; ++mf)
                #pragma unroll
                for (int r = 0; r < 4; ++r) {
                    int t = (m0 & 2047) + wm * 128 + mf * 16 + quad * 4 + r;
                    qb[((size_t)(b * HH + h) * TT + t) * HS + d] = f2bf(acc[mf][nf][r] * QSCALE);
                }
        } else if (which == 1) {
            #pragma unroll
            for (int mf = 0; mf < 8; ++mf)
                #pragma unroll
                for (int r = 0; r < 4; ++r) {
                    int t = (m0 & 2047) + wm * 128 + mf * 16 + quad * 4 + r;
                    kb[((size_t)(b * HH + h) * TT + t) * HS + d] = f2bf(acc[mf][nf][r]);
                }
        } else {
            #pragma unroll
            for (int a = 0; a < 4; ++a) {     // pairs (2a,2a+1) -> 32-key block
                bf16x8 pv;
                #pragma unroll
                for (int r = 0; r < 4; ++r) {
                    pv[r * 2]     = f2bf(acc[2 * a][nf][r]);
                    pv[r * 2 + 1] = f2bf(acc[2 * a + 1][nf][r]);
                }
                int tb2 = (m0 & 2047) + wm * 128 + a * 32;
                *(bf16x8*)(vt + ((size_t)(b * HH + h) * HS + d) * TT + tb2 + quad * 8) = pv;
            }
        }
    }
}

// block schedule: (qg, c) sorted by trip count desc; c=-1 = unsplit (qg<16)
__device__ static const signed char ORD[48][2] = {
    {15,-1},{31,0},{31,1},{30,0},{30,1},
    {14,-1},{29,0},{29,1},{28,0},{28,1},
    {13,-1},{27,0},{27,1},{26,0},{26,1},
    {12,-1},{25,0},{25,1},{24,0},{24,1},
    {11,-1},{23,0},{23,1},{22,0},{22,1},
    {10,-1},{21,0},{21,1},{20,0},{20,1},
    { 9,-1},{19,0},{19,1},{18,0},{18,1},
    { 8,-1},{17,0},{17,1},{16,0},{16,1},
    { 7,-1},{ 6,-1},{ 5,-1},{ 4,-1},{ 3,-1},{ 2,-1},{ 1,-1},{ 0,-1}
};

// ---------------------------------------------------------------- attention (partials, no atomics)
// Unsplit (qg<16): ones-MFMA rowsum is lane-local (C-layout is col-
// independent) -> normalize in-register and write bf16 yb DIRECTLY.
// Split (qg>=16): c=0 -> o0/l0, c=1 -> o1/l1 plain stores; k_norm combines.
// P software-pipelined one tile (ping-pong parity buffers), no in-loop
// lgkmcnt(0). Cooperative double-buffered K/V LDS staging, 1 barrier/iter.
__global__ __launch_bounds__(128, 2) void k_attn(const bf16_t* __restrict__ qb,
                                                 const bf16_t* __restrict__ kb,
                                                 const bf16_t* __restrict__ vt,
                                                 bf16_t* __restrict__ yb,
                                                 float* __restrict__ o0,
                                                 float* __restrict__ o1,
                                                 float* __restrict__ l0,
                                                 float* __restrict__ l1) {
    __shared__ bf16_t Kb[2][32 * 72];      // key row stride 144B
    __shared__ bf16_t Vb[2][64 * 40];      // d row stride 80B
    __shared__ bf16_t Ps[2][2][32 * PST2]; // [wave][parity]
    const int tid = threadIdx.x;
    const int w = tid >> 6, lane = tid & 63;
    const int quad = lane >> 4, lrow = lane & 15;
    const int bh = blockIdx.x & 31;
    const int j = blockIdx.x >> 5;                 // 0..47
    const int qg = ORD[j][0];
    const int cc = ORD[j][1];                      // -1 = unsplit
    const int ct = (cc < 0) ? (2 * qg + 2) : (qg + 1);
    const int key0 = (cc == 1) ? (qg + 1) * 32 : 0;
    const int kendl = 2 * qg + w + 1 - ((cc == 1) ? (qg + 1) : 0);
    const int kw = min(kendl, ct);
    const int q0 = qg * 64 + w * 32;

    const bf16_t* Qg = qb + (size_t)bh * TT * HS;
    const bf16_t* Kg = kb + (size_t)bh * TT * HS;
    const bf16_t* Vg = vt + (size_t)bh * HS * TT;

    const int skey = tid >> 2, scol = (tid & 3) * 16;
    const int svrow = tid >> 1, svcol = (tid & 1) * 16;

    bf16x8 kra, krb, vra, vrb;
    {   // prestage tile 0
        const bf16_t* gk = Kg + (size_t)(key0 + skey) * HS + scol;
        kra = *(const bf16x8*)(gk);
        krb = *(const bf16x8*)(gk + 8);
        const bf16_t* gv = Vg + (size_t)svrow * TT + key0 + svcol;
        vra = *(const bf16x8*)(gv);
        vrb = *(const bf16x8*)(gv + 8);
        *(bf16x8*)(&Kb[0][skey * 72 + scol])     = kra;
        *(bf16x8*)(&Kb[0][skey * 72 + scol + 8]) = krb;
        *(bf16x8*)(&Vb[0][svrow * 40 + svcol])     = vra;
        *(bf16x8*)(&Vb[0][svrow * 40 + svcol + 8]) = vrb;
    }

    bf16x8 aq[2][2];
    for (int tq = 0; tq < 2; ++tq)
        for (int c = 0; c < 2; ++c)
            aq[tq][c] = *(const bf16x8*)(Qg + (size_t)(q0 + tq * 16 + lrow) * HS + c * 32 + quad * 8);

    const bf16_t onebf = __builtin_bit_cast(bf16_t, (unsigned short)0x3F80);
    bf16x8 bones = {onebf, onebf, onebf, onebf, onebf, onebf, onebf, onebf};

    floatx4 o[2][4];
    for (int tq = 0; tq < 2; ++tq)
        for (int dc = 0; dc < 4; ++dc) o[tq][dc] = floatx4{0.f, 0.f, 0.f, 0.f};
    floatx4 ol[2] = {floatx4{0.f,0.f,0.f,0.f}, floatx4{0.f,0.f,0.f,0.f}};

    bf16x8 bv_sav[4];
    const int wrow0 = quad * 4;

    for (int t = 0; t < ct; ++t) {
        __syncthreads();   // staging writes of t (done at end of t-1) visible
        if (t + 1 < ct) {  // post-barrier prefetch of next tile into regs
            const bf16_t* gk = Kg + (size_t)(key0 + (t + 1) * 32 + skey) * HS + scol;
            kra = *(const bf16x8*)(gk);
            krb = *(const bf16x8*)(gk + 8);
            const bf16_t* gv = Vg + (size_t)svrow * TT + key0 + (t + 1) * 32 + svcol;
            vra = *(const bf16x8*)(gv);
            vrb = *(const bf16x8*)(gv + 8);
        }
        if (t < kw) {
            // ---- deferred PV for tile t-1 (P from parity buffer, V from regs)
            if (t > 0) {
                const bf16_t* Pp = &Ps[w][(t - 1) & 1][0];
                bf16x8 pa0 = *(const bf16x8*)(Pp + (size_t)lrow * PST2 + quad * 8);
                bf16x8 pa1 = *(const bf16x8*)(Pp + (size_t)(16 + lrow) * PST2 + quad * 8);
                o[0][0] = __builtin_amdgcn_mfma_f32_16x16x32_bf16(pa0, bv_sav[0], o[0][0], 0, 0, 0);
                o[0][1] = __builtin_amdgcn_mfma_f32_16x16x32_bf16(pa0, bv_sav[1], o[0][1], 0, 0, 0);
                o[0][2] = __builtin_amdgcn_mfma_f32_16x16x32_bf16(pa0, bv_sav[2], o[0][2], 0, 0, 0);
                o[0][3] = __builtin_amdgcn_mfma_f32_16x16x32_bf16(pa0, bv_sav[3], o[0][3], 0, 0, 0);
                ol[0]   = __builtin_amdgcn_mfma_f32_16x16x32_bf16(pa0, bones, ol[0], 0, 0, 0);
                o[1][0] = __builtin_amdgcn_mfma_f32_16x16x32_bf16(pa1, bv_sav[0], o[1][0], 0, 0, 0);
                o[1][1] = __builtin_amdgcn_mfma_f32_16x16x32_bf16(pa1, bv_sav[1], o[1][1], 0, 0, 0);
                o[1][2] = __builtin_amdgcn_mfma_f32_16x16x32_bf16(pa1, bv_sav[2], o[1][2], 0, 0, 0);
                o[1][3] = __builtin_amdgcn_mfma_f32_16x16x32_bf16(pa1, bv_sav[3], o[1][3], 0, 0, 0);
                ol[1]   = __builtin_amdgcn_mfma_f32_16x16x32_bf16(pa1, bones, ol[1], 0, 0, 0);
            }
            // ---- QK^T for tile t
            const bf16_t* Kt = &Kb[t & 1][0];
            const bf16_t* Vt = &Vb[t & 1][0];
            bf16x8 bk0 = *(const bf16x8*)(Kt + lrow * 72 + quad * 8);
            bf16x8 bk1 = *(const bf16x8*)(Kt + lrow * 72 + 32 + quad * 8);
            bf16x8 bk2 = *(const bf16x8*)(Kt + (16 + lrow) * 72 + quad * 8);
            bf16x8 bk3 = *(const bf16x8*)(Kt + (16 + lrow) * 72 + 32 + quad * 8);
            floatx4 s00 = floatx4{0.f,0.f,0.f,0.f}, s01 = s00, s10 = s00, s11 = s00;
            s00 = __builtin_amdgcn_mfma_f32_16x16x32_bf16(aq[0][0], bk0, s00, 0, 0, 0);
            s00 = __builtin_amdgcn_mfma_f32_16x16x32_bf16(aq[0][1], bk1, s00, 0, 0, 0);
            s01 = __builtin_amdgcn_mfma_f32_16x16x32_bf16(aq[0][0], bk2, s01, 0, 0, 0);
            s01 = __builtin_amdgcn_mfma_f32_16x16x32_bf16(aq[0][1], bk3, s01, 0, 0, 0);
            s10 = __builtin_amdgcn_mfma_f32_16x16x32_bf16(aq[1][0], bk0, s10, 0, 0, 0);
            s10 = __builtin_amdgcn_mfma_f32_16x16x32_bf16(aq[1][1], bk1, s10, 0, 0, 0);
            s11 = __builtin_amdgcn_mfma_f32_16x16x32_bf16(aq[1][0], bk2, s11, 0, 0, 0);
            s11 = __builtin_amdgcn_mfma_f32_16x16x32_bf16(aq[1][1], bk3, s11, 0, 0, 0);

            bv_sav[0] = *(const bf16x8*)(Vt + (0  + lrow) * 40 + quad * 8);
            bv_sav[1] = *(const bf16x8*)(Vt + (16 + lrow) * 40 + quad * 8);
            bv_sav[2] = *(const bf16x8*)(Vt + (32 + lrow) * 40 + quad * 8);
            bv_sav[3] = *(const bf16x8*)(Vt + (48 + lrow) * 40 + quad * 8);

            uint32_t* P32 = (uint32_t*)(&Ps[w][t & 1][0]);
            if (t < kendl - 1) {            // unmasked tile
                for (int r = 0; r < 4; ++r) {
                    float e00 = __builtin_amdgcn_exp2f(s00[r]);
                    float e01 = __builtin_amdgcn_exp2f(s01[r]);
                    float e10 = __builtin_amdgcn_exp2f(s10[r]);
                    float e11 = __builtin_amdgcn_exp2f(s11[r]);
                    uint32_t pk0 = __builtin_amdgcn_perm(
                        __builtin_bit_cast(uint32_t, e01),
                        __builtin_bit_cast(uint32_t, e00), 0x07060302u);
                    uint32_t pk1 = __builtin_amdgcn_perm(
                        __builtin_bit_cast(uint32_t, e11),
                        __builtin_bit_cast(uint32_t, e10), 0x07060302u);
                    P32[(wrow0 + r) * 20 + lrow]      = pk0;
                    P32[(wrow0 + r + 16) * 20 + lrow] = pk1;
                }
            } else {                        // diagonal tile (keys start at q0)
                for (int r = 0; r < 4; ++r) {
                    bool keep = lrow <= quad * 4 + r;
                    float e00 = keep ? __builtin_amdgcn_exp2f(s00[r]) : 0.f;
                    float e01 = 0.f; (void)s01;
                    float e10 = __builtin_amdgcn_exp2f(s10[r]);
                    float e11 = keep ? __builtin_amdgcn_exp2f(s11[r]) : 0.f;
                    uint32_t pk0 = __builtin_amdgcn_perm(
                        __builtin_bit_cast(uint32_t, e01),
                        __builtin_bit_cast(uint32_t, e00), 0x07060302u);
                    uint32_t pk1 = __builtin_amdgcn_perm(
                        __builtin_bit_cast(uint32_t, e11),
                        __builtin_bit_cast(uint32_t, e10), 0x07060302u);
                    P32[(wrow0 + r) * 20 + lrow]      = pk0;
                    P32[(wrow0 + r + 16) * 20 + lrow] = pk1;
                }
            }
        }
        if (t + 1 < ct) {   // write staged K/V into the other buffer
            bf16_t* Kn = &Kb[(t + 1) & 1][0];
            bf16_t* Vn = &Vb[(t + 1) & 1][0];
            *(bf16x8*)(Kn + skey * 72 + scol)     = kra;
            *(bf16x8*)(Kn + skey * 72 + scol + 8) = krb;
            *(bf16x8*)(Vn + svrow * 40 + svcol)     = vra;
            *(bf16x8*)(Vn + svrow * 40 + svcol + 8) = vrb;
        }
    }

    // ---- final deferred PV (tile kw-1)
    asm volatile("s_waitcnt lgkmcnt(0)" ::: "memory");
    {
        const bf16_t* Pp = &Ps[w][(kw - 1) & 1][0];
        bf16x8 pa0 = *(const bf16x8*)(Pp + (size_t)lrow * PST2 + quad * 8);
        bf16x8 pa1 = *(const bf16x8*)(Pp + (size_t)(16 + lrow) * PST2 + quad * 8);
        o[0][0] = __builtin_amdgcn_mfma_f32_16x16x32_bf16(pa0, bv_sav[0], o[0][0], 0, 0, 0);
        o[0][1] = __builtin_amdgcn_mfma_f32_16x16x32_bf16(pa0, bv_sav[1], o[0][1], 0, 0, 0);
        o[0][2] = __builtin_amdgcn_mfma_f32_16x16x32_bf16(pa0, bv_sav[2], o[0][2], 0, 0, 0);
        o[0][3] = __builtin_amdgcn_mfma_f32_16x16x32_bf16(pa0, bv_sav[3], o[0][3], 0, 0, 0);
        ol[0]   = __builtin_amdgcn_mfma_f32_16x16x32_bf16(pa0, bones, ol[0], 0, 0, 0);
        o[1][0] = __builtin_amdgcn_mfma_f32_16x16x32_bf16(pa1, bv_sav[0], o[1][0], 0, 0, 0);
        o[1][1] = __builtin_amdgcn_mfma_f32_16x16x32_bf16(pa1, bv_sav[1], o[1][1], 0, 0, 0);
        o[1][2] = __builtin_amdgcn_mfma_f32_16x16x32_bf16(pa1, bv_sav[2], o[1][2], 0, 0, 0);
        o[1][3] = __builtin_amdgcn_mfma_f32_16x16x32_bf16(pa1, bv_sav[3], o[1][3], 0, 0, 0);
        ol[1]   = __builtin_amdgcn_mfma_f32_16x16x32_bf16(pa1, bones, ol[1], 0, 0, 0);
    }

    // ---- epilogue
    if (cc < 0) {           // unsplit: normalize locally, write yb directly
        const int b = bh >> 4, h = bh & 15;
        for (int tq = 0; tq < 2; ++tq)
            for (int r = 0; r < 4; ++r) {
                float inv = 1.0f / ol[tq][r];
                int q = q0 + tq * 16 + quad * 4 + r;
                for (int dc = 0; dc < 4; ++dc)
                    yb[(size_t)(b * TT + q) * CC + h * HS + dc * 16 + lrow] =
                        f2bf(o[tq][dc][r] * inv);
            }
    } else if (cc == 1) {   // split back half
        for (int tq = 0; tq < 2; ++tq)
            for (int r = 0; r < 4; ++r) {
                int q = q0 + tq * 16 + quad * 4 + r;
                float* dst = o1 + ((size_t)(bh * 16 + qg - 16) * 64 + (q - qg * 64)) * 64 + lrow;
                for (int dc = 0; dc < 4; ++dc) dst[dc * 16] = o[tq][dc][r];
                if (lrow == 0) l1[(size_t)(bh * 16 + qg - 16) * 64 + (q - qg * 64)] = ol[tq][r];
            }
    } else {                // split front half
        for (int tq = 0; tq < 2; ++tq)
            for (int r = 0; r < 4; ++r) {
                int q = q0 + tq * 16 + quad * 4 + r;
                float* dst = o0 + ((size_t)bh * TT + q) * HS + lrow;
                for (int dc = 0; dc < 4; ++dc) dst[dc * 16] = o[tq][dc][r];
                if (lrow == 0) l0[(size_t)bh * TT + q] = ol[tq][r];
            }
    }
}

// ---------------------------------------------------------------- normalize + combine (split rows only, q>=1024)
__global__ __launch_bounds__(256) void k_norm(const float* __restrict__ o0,
                                              const float* __restrict__ o1,
                                              const float* __restrict__ l0,
                                              const float* __restrict__ l1,
                                              bf16_t* __restrict__ yb) {
    int idx = blockIdx.x * 256 + threadIdx.x;      // over 32 bh x 1024 q x 8
    int d8 = idx & 7;
    int q  = 1024 + ((idx >> 3) & 1023);
    int bh = idx >> 13;
    int qg = q >> 6;
    const float* s0 = o0 + ((size_t)bh * TT + q) * HS + d8 * 8;
    const float* s1 = o1 + ((size_t)(bh * 16 + qg - 16) * 64 + (q & 63)) * 64 + d8 * 8;
    float4 a = *(const float4*)(s0);
    float4 b = *(const float4*)(s0 + 4);
    float4 a1 = *(const float4*)(s1);
    float4 b1 = *(const float4*)(s1 + 4);
    a.x += a1.x; a.y += a1.y; a.z += a1.z; a.w += a1.w;
    b.x += b1.x; b.y += b1.y; b.z += b1.z; b.w += b1.w;
    float l = l0[(size_t)bh * TT + q] + l1[(size_t)(bh * 16 + qg - 16) * 64 + (q & 63)];
    float inv = 1.0f / l;
    bf16x8 r;
    r[0] = f2bf(a.x * inv); r[1] = f2bf(a.y * inv);
    r[2] = f2bf(a.z * inv); r[3] = f2bf(a.w * inv);
    r[4] = f2bf(b.x * inv); r[5] = f2bf(b.y * inv);
    r[6] = f2bf(b.z * inv); r[7] = f2bf(b.w * inv);
    int bb = bh >> 4, h = bh & 15;
    *(bf16x8*)(yb + ((size_t)(bb * TT + q)) * CC + h * HS + d8 * 8) = r;
}

// ---------------------------------------------------------------- out GEMM (fp32 out + bias)
// r4 ring structure ported (r6-verified win): 128x64 tile, 256 threads, 4-slot
// LDS ring (48 KB -> 3 blocks/CU), counted vmcnt(6), pre-swizzled source +
// swizzled ds_read, setprio. 512 blocks + bijective XCD swizzle.
__global__ __launch_bounds__(256, 2) void k_gemm_out(const bf16_t* __restrict__ yin,
                                                     const bf16_t* __restrict__ Wt,
                                                     const float* __restrict__ bias,
                                                     float* __restrict__ out) {
    __shared__ bf16_t As[4][128 * 32];   // 8 KB/slot
    __shared__ bf16_t Bs[4][64 * 32];    // 4 KB/slot -> 48 KB total
    const int tid = threadIdx.x;
    const int wave = tid >> 6, lane = tid & 63;
    const int quad = lane >> 4, lrow = lane & 15;
    const int wm = wave >> 1, wn = wave & 1;         // 2x2 wave grid, 64x32/wave

    const int bid = blockIdx.y * 16 + blockIdx.x;
    const int swz = (bid & 7) * 64 + (bid >> 3);     // 64 contiguous tiles/XCD
    const int m0 = (swz >> 4) * 128, n0 = (swz & 15) * 64;

    floatx4 acc[4][2];
    #pragma unroll
    for (int i = 0; i < 4; ++i)
        #pragma unroll
        for (int j = 0; j < 2; ++j) acc[i][j] = floatx4{0.f, 0.f, 0.f, 0.f};

    // per K-tile: A = 512 chunks (2/thread), B = 256 chunks (1/thread) -> 3
    // uniform loads/thread. Pre-swizzled source gc = cs ^ ((row>>1)&3).
    auto stage = [&](int kt) {
        const int slot = kt & 3;
        const int kk = kt * 32;
        #pragma unroll
        for (int l = 0; l < 2; ++l) {
            int L = l * 256 + tid;
            int row = L >> 2, cs = L & 3;
            int gc = cs ^ ((row >> 1) & 3);
            load_lds16(yin + (size_t)(m0 + row) * CC + kk + gc * 8,
                       &As[slot][(size_t)(l * 256 + wave * 64) * 8]);
        }
        {
            int row = tid >> 2, cs = tid & 3;
            int gc = cs ^ ((row >> 1) & 3);
            load_lds16(Wt + (size_t)(n0 + row) * CC + kk + gc * 8,
                       &Bs[slot][(size_t)(wave * 64) * 8]);
        }
    };

    const int csw = (quad ^ ((lrow >> 1) & 3)) * 8;

    auto do_tile = [&](int kt, bool st) {
        const bf16_t* Ab = &As[kt & 3][0];
        const bf16_t* Bb = &Bs[kt & 3][0];
        bf16x8 af[4], bfr[2];
        #pragma unroll
        for (int i = 0; i < 4; ++i)
            af[i] = *(const bf16x8*)(Ab + (wm * 64 + i * 16 + lrow) * 32 + csw);
        #pragma unroll
        for (int j = 0; j < 2; ++j)
            bfr[j] = *(const bf16x8*)(Bb + (wn * 32 + j * 16 + lrow) * 32 + csw);
        if (st) stage(kt + 3);
        __builtin_amdgcn_s_barrier();
        __builtin_amdgcn_s_setprio(1);
        #pragma unroll
        for (int i = 0; i < 4; ++i)
            #pragma unroll
            for (int j = 0; j < 2; ++j)
                acc[i][j] = __builtin_amdgcn_mfma_f32_16x16x32_bf16(af[i], bfr[j], acc[i][j], 0, 0, 0);
        __builtin_amdgcn_s_setprio(0);
    };

    // prologue: 3 tiles in flight (9 loads/thread); tile0 ready at vmcnt(6)
    stage(0); stage(1); stage(2);
    asm volatile("s_waitcnt vmcnt(6)" ::: "memory");
    __builtin_amdgcn_s_barrier();

    for (int kt = 0; kt < 29; ++kt) {
        do_tile(kt, true);
        asm volatile("s_waitcnt vmcnt(6)" ::: "memory");
        __builtin_amdgcn_s_barrier();
    }
    // drain 6 -> 3 -> 0
    do_tile(29, false);
    asm volatile("s_waitcnt vmcnt(3)" ::: "memory");
    __builtin_amdgcn_s_barrier();
    do_tile(30, false);
    asm volatile("s_waitcnt vmcnt(0)" ::: "memory");
    __builtin_amdgcn_s_barrier();
    do_tile(31, false);

    #pragma unroll
    for (int i = 0; i < 4; ++i)
        #pragma unroll
        for (int j = 0; j < 2; ++j) {
            int gn = n0 + wn * 32 + j * 16 + lrow;
            float bb = bias[gn];
            #pragma unroll
            for (int r = 0; r < 4; ++r) {
                int gm = m0 + wm * 64 + i * 16 + quad * 4 + r;
                out[(size_t)gm * CC + gn] = acc[i][j][r] + bb;
            }
        }
}

// ---------------------------------------------------------------- launch
extern "C" void kernel_launch(void* const* d_in, const int* in_sizes, int n_in,
                              void* d_out, int out_size, void* d_ws, size_t ws_size,
                              hipStream_t stream) {
    (void)in_sizes; (void)n_in; (void)out_size; (void)ws_size;
    const float* x    = (const float*)d_in[0];  // [2,2048,1024] fp32
    const float* Wqkv = (const float*)d_in[1];  // [1024,3072]   fp32
    const float* Wout = (const float*)d_in[2];  // [1024,1024]   fp32
    const float* bout = (const float*)d_in[3];  // [1024]        fp32
    float* out = (float*)d_out;                 // [2,2048,1024] fp32

    bf16_t* xb  = (bf16_t*)d_ws;                        // [4096][1024]  8 MB
    bf16_t* Wt1 = xb + (size_t)MM * CC;                 // [3072][1024]  6 MB
    bf16_t* Wt2 = Wt1 + (size_t)N1 * CC;                // [1024][1024]  2 MB
    bf16_t* qb  = Wt2 + (size_t)CC * CC;                // [B,H,T,hs]    8 MB
    bf16_t* kb  = qb + (size_t)BB * HH * TT * HS;       // [B,H,T,hs]    8 MB
    bf16_t* vb  = kb + (size_t)BB * HH * TT * HS;       // [B,H,hs,T~]   8 MB (perm)
    bf16_t* yb  = vb + (size_t)BB * HH * TT * HS;       // [B,T,C] bf16  8 MB
    float*  o0  = (float*)d_out; // 16 MB partial-0; dead before k_gemm_out writes
    float*  o1  = (float*)xb;    // 8 MB partial-1; xb dead after k_gemm_qkv
    float*  l0  = (float*)Wt1;   // 256 KB; Wt1 dead after k_gemm_qkv
    float*  l1  = l0 + (size_t)BB * HH * TT;            // 128 KB

    k_prep<<<dim3(2048 + 3072 + 1024), 256, 0, stream>>>(x, Wqkv, Wout, xb, Wt1, Wt2);
    k_gemm_qkv<<<dim3(12, 16), 512, 0, stream>>>(xb, Wt1, qb, kb, vb);
    k_attn<<<dim3(48 * 32), 128, 0, stream>>>(qb, kb, vb, yb, o0, o1, l0, l1);
    k_norm<<<dim3(1024), 256, 0, stream>>>(o0, o1, l0, l1, yb);
    k_gemm_out<<<dim3(CC / 64, MM / 128), 256, 0, stream>>>(yb, Wt2, bout, out);
}

// Round 12
// 166.475 us; speedup vs baseline: 1.0294x; 1.0294x over previous
//
#include <hip/hip_runtime.h>
#include <cstdint>
#include <cstddef>

// Problem constants (from reference): B=2, T=2048, C=1024, H=16, hs=64
// Harness dtypes: inputs fp32, output fp32; internal compute bf16 MFMA.
#define BB 2
#define TT 2048
#define CC 1024
#define HH 16
#define HS 64
#define MM (BB*TT)      // 4096 rows
#define N1 (3*CC)       // 3072 qkv cols

// P-scratch row stride in elements (80 B/row)
#define PST2 40

// q prescale: hs^-0.5 * log2(e)  -> softmax_e(s) == softmax_2(s*log2e)
#define QSCALE 0.1803368801111243f

typedef __bf16 bf16_t;
typedef bf16_t bf16x8 __attribute__((ext_vector_type(8)));
typedef float  floatx4 __attribute__((ext_vector_type(4)));

__device__ __forceinline__ bf16_t f2bf(float f) {
    uint32_t u = __builtin_bit_cast(uint32_t, f);
    u += 0x7FFFu + ((u >> 16) & 1u);   // round-to-nearest-even
    unsigned short s = (unsigned short)(u >> 16);
    return __builtin_bit_cast(bf16_t, s);
}

__device__ __forceinline__ void load_lds16(const bf16_t* g, bf16_t* l) {
    __builtin_amdgcn_global_load_lds((__attribute__((address_space(1))) void*)g,
                                     (__attribute__((address_space(3))) void*)l,
                                     16, 0, 0);
}

// ---------------------------------------------------------------- prep (pack x + transpose both weights)
__device__ __forceinline__ void transpose_body(const float* __restrict__ src,
                                               bf16_t* __restrict__ dst,
                                               int R, int Ccol, int bx, int by,
                                               int tx, int ty, bf16_t (*tile)[33]) {
    int c0 = bx * 32, r0 = by * 32;
    for (int i = ty; i < 32; i += 8)
        tile[i][tx] = f2bf(src[(size_t)(r0 + i) * Ccol + c0 + tx]);
    __syncthreads();
    for (int i = ty; i < 32; i += 8)
        dst[(size_t)(c0 + i) * R + r0 + tx] = tile[tx][i];
}

__global__ __launch_bounds__(256) void k_prep(const float* __restrict__ x,
                                              const float* __restrict__ Wqkv,
                                              const float* __restrict__ Wout,
                                              bf16_t* __restrict__ xb,
                                              bf16_t* __restrict__ Wt1,
                                              bf16_t* __restrict__ Wt2) {
    __shared__ bf16_t tile[32][33];
    const int bid = blockIdx.x, tid = threadIdx.x;
    if (bid < 2048) {                       // pack x: 4M elems, 8/thread
        size_t i = ((size_t)bid * 256 + tid) * 8;
        float4 a = *(const float4*)(x + i);
        float4 b = *(const float4*)(x + i + 4);
        bf16x8 o;
        o[0] = f2bf(a.x); o[1] = f2bf(a.y); o[2] = f2bf(a.z); o[3] = f2bf(a.w);
        o[4] = f2bf(b.x); o[5] = f2bf(b.y); o[6] = f2bf(b.z); o[7] = f2bf(b.w);
        *(bf16x8*)(xb + i) = o;
    } else if (bid < 2048 + 3072) {         // Wqkv^T: grid (96,32)
        int bb = bid - 2048;
        transpose_body(Wqkv, Wt1, CC, N1, bb % 96, bb / 96, tid & 31, tid >> 5, tile);
    } else {                                // Wout^T: grid (32,32)
        int bb = bid - 5120;
        transpose_body(Wout, Wt2, CC, CC, bb & 31, bb >> 5, tid & 31, tid >> 5, tile);
    }
}

// ---------------------------------------------------------------- QKV GEMM: 256x192 tile -> 16x16 = 256
// blocks = 1/CU (100% fill). 8 waves (2Mx4N), per-wave 128x48. 4-slot LDS ring
// (r4/r6-verified best), counted vmcnt (T4), pre-swizzled source + swizzled
// ds_read (T2), setprio (T5), COARSE single-phase K-tile (24 MFMA).
// SESSION LEDGER (do not re-attempt): fine-phase pins (r2 -7us), 2-phase split
// (r5 -9us), 128^2 ring (r7 -6us), LDS-bounce epilogue (r9 -4us), BK=64 3-gate
// @192 blocks (r11 -3us). No B-pad re-loads (r8): per-wave vmcnt
// (8/4/0 waves 0-3, 6/3/0 waves 4-7). v fused: transposed + sigma-packed.
__global__ __launch_bounds__(512) void k_gemm_qkv(const bf16_t* __restrict__ x,
                                                  const bf16_t* __restrict__ Wt,
                                                  bf16_t* __restrict__ qb,
                                                  bf16_t* __restrict__ kb,
                                                  bf16_t* __restrict__ vt) {
    // ring: per slot A[256][32], B[192(+unused 64)][32] bf16 -> 4*(16+16) KiB = 128 KiB
    __shared__ bf16_t As[4][256 * 32];
    __shared__ bf16_t Bs[4][256 * 32];
    const int tid = threadIdx.x;
    const int wave = tid >> 6, lane = tid & 63;
    const int quad = lane >> 4, lrow = lane & 15;
    const int wm = wave >> 2, wn = wave & 3;

    // bijective XCD swizzle: 256 blocks, 32 contiguous tiles per XCD
    const int bid = blockIdx.y * 16 + blockIdx.x;
    const int swz = (bid & 7) * 32 + (bid >> 3);
    const int m0 = (swz >> 4) * 256, n0 = (swz & 15) * 192;

    floatx4 acc[8][3];
    #pragma unroll
    for (int i = 0; i < 8; ++i)
        #pragma unroll
        for (int j = 0; j < 3; ++j) acc[i][j] = floatx4{0.f, 0.f, 0.f, 0.f};

    // staging: per K-tile, A = 1024 16B-chunks (2/thread), B = 768 chunks
    // (2/thread for waves 0-3, 1/thread for waves 4-7; the L<768 condition is
    // wave-uniform). LDS dest LINEAR (global_load_lds = wave-uniform base +
    // lane*16); bank swizzle via PRE-SWIZZLED global source chunk
    // gc = cs ^ ((row>>1)&3).
    auto stage = [&](int kt) {
        const int slot = kt & 3;
        const int kk = kt * 32;
        #pragma unroll
        for (int l = 0; l < 2; ++l) {
            int L = l * 512 + tid;
            {   // A chunk
                int row = L >> 2, cs = L & 3;
                int gc = cs ^ ((row >> 1) & 3);
                load_lds16(x + (size_t)(m0 + row) * CC + kk + gc * 8,
                           &As[slot][(size_t)(l * 512 + wave * 64) * 8]);
            }
            if (L < 768) {   // B chunk (no pad re-loads)
                int row = L >> 2, cs = L & 3;
                int gc = cs ^ ((row >> 1) & 3);
                load_lds16(Wt + (size_t)(n0 + row) * CC + kk + gc * 8,
                           &Bs[slot][(size_t)(l * 512 + wave * 64) * 8]);
            }
        }
    };

    const int csw = (quad ^ ((lrow >> 1) & 3)) * 8;   // swizzled 8-elem chunk

    // one K-tile: 11 swizzled ds_read_b128 + stage issue, barrier, 24 MFMA
    // under setprio. Reads of slot kt&3 safe (per-wave vmcnt + barrier of
    // kt-1); stage into slot (kt+3)&3 == (kt-1)&3 safe (reads done pre-barrier).
    auto do_tile = [&](int kt, bool st) {
        const bf16_t* Ab = &As[kt & 3][0];
        const bf16_t* Bb = &Bs[kt & 3][0];
        bf16x8 af[8], bfr[3];
        #pragma unroll
        for (int mf = 0; mf < 8; ++mf)
            af[mf] = *(const bf16x8*)(Ab + (wm * 128 + mf * 16 + lrow) * 32 + csw);
        #pragma unroll
        for (int nf = 0; nf < 3; ++nf)
            bfr[nf] = *(const bf16x8*)(Bb + (wn * 48 + nf * 16 + lrow) * 32 + csw);
        if (st) stage(kt + 3);
        __builtin_amdgcn_s_barrier();
        __builtin_amdgcn_s_setprio(1);
        #pragma unroll
        for (int mf = 0; mf < 8; ++mf)
            #pragma unroll
            for (int nf = 0; nf < 3; ++nf)
                acc[mf][nf] = __builtin_amdgcn_mfma_f32_16x16x32_bf16(af[mf], bfr[nf], acc[mf][nf], 0, 0, 0);
        __builtin_amdgcn_s_setprio(0);
    };

    // per-wave waits: waves 0-3 carry 4 loads/tile, waves 4-7 carry 3.
    // "N tiles in flight" => vmcnt(4N) / vmcnt(3N). If the compiler exec-masks
    // instead of branching, both (stricter) waits run -- still correct.

    // prologue: 3 tiles in flight; tile0 ready when 2 tiles remain outstanding
    stage(0); stage(1); stage(2);
    if (wave < 4) asm volatile("s_waitcnt vmcnt(8)" ::: "memory");
    else          asm volatile("s_waitcnt vmcnt(6)" ::: "memory");
    __builtin_amdgcn_s_barrier();

    // main: tiles kt+2,kt+3 stay in flight
    for (int kt = 0; kt < 29; ++kt) {
        do_tile(kt, true);
        if (wave < 4) asm volatile("s_waitcnt vmcnt(8)" ::: "memory");
        else          asm volatile("s_waitcnt vmcnt(6)" ::: "memory");
        __builtin_amdgcn_s_barrier();
    }
    // epilogue drain: 2 -> 1 -> 0 tiles in flight
    do_tile(29, false);
    if (wave < 4) asm volatile("s_waitcnt vmcnt(4)" ::: "memory");
    else          asm volatile("s_waitcnt vmcnt(3)" ::: "memory");
    __builtin_amdgcn_s_barrier();
    do_tile(30, false);
    asm volatile("s_waitcnt vmcnt(0)" ::: "memory");
    __builtin_amdgcn_s_barrier();
    do_tile(31, false);

    // ---- epilogue: q (prescaled), k natural, v transposed + sigma-packed
    const int b = m0 >> 11;                  // whole block in one batch row
    #pragma unroll
    for (int nf = 0; nf < 3; ++nf) {
        int gn = n0 + wn * 48 + nf * 16 + lrow;
        int which = gn >> 10, c = gn & 1023, h = c >> 6, d = c & 63;
        if (which == 0) {
            #pragma unroll
            for (int mf = 0; mf < 8; ++mf)
                #pragma unroll
                for (int r = 0; r < 4; ++r) {
                    int t = (m0 & 2047) + wm * 128 + mf * 16 + quad * 4 + r;
                    qb[((size_t)(b * HH + h) * TT + t) * HS + d] = f2bf(acc[mf][nf][r] * QSCALE);
                }
        } else if (which == 1) {
            #pragma unroll
            for (int mf = 0; mf < 8; ++mf)
                #pragma unroll
                for (int r = 0; r < 4; ++r) {
                    int t = (m0 & 2047) + wm * 128 + mf * 16 + quad * 4 + r;
                    kb[((size_t)(b * HH + h) * TT + t) * HS + d] = f2bf(acc[mf][nf][r]);
                }
        } else {
            #pragma unroll
            for (int a = 0; a < 4; ++a) {     // pairs (2a,2a+1) -> 32-key block
                bf16x8 pv;
                #pragma unroll
                for (int r = 0; r < 4; ++r) {
                    pv[r * 2]     = f2bf(acc[2 * a][nf][r]);
                    pv[r * 2 + 1] = f2bf(acc[2 * a + 1][nf][r]);
                }
                int tb2 = (m0 & 2047) + wm * 128 + a * 32;
                *(bf16x8*)(vt + ((size_t)(b * HH + h) * HS + d) * TT + tb2 + quad * 8) = pv;
            }
        }
    }
}

// block schedule: (qg, c) sorted by trip count desc; c=-1 = unsplit (qg<16)
__device__ static const signed char ORD[48][2] = {
    {15,-1},{31,0},{31,1},{30,0},{30,1},
    {14,-1},{29,0},{29,1},{28,0},{28,1},
    {13,-1},{27,0},{27,1},{26,0},{26,1},
    {12,-1},{25,0},{25,1},{24,0},{24,1},
    {11,-1},{23,0},{23,1},{22,0},{22,1},
    {10,-1},{21,0},{21,1},{20,0},{20,1},
    { 9,-1},{19,0},{19,1},{18,0},{18,1},
    { 8,-1},{17,0},{17,1},{16,0},{16,1},
    { 7,-1},{ 6,-1},{ 5,-1},{ 4,-1},{ 3,-1},{ 2,-1},{ 1,-1},{ 0,-1}
};

// ---------------------------------------------------------------- attention (partials, no atomics)
// Unsplit (qg<16): ones-MFMA rowsum is lane-local (C-layout is col-
// independent) -> normalize in-register and write bf16 yb DIRECTLY.
// Split (qg>=16): c=0 -> o0/l0, c=1 -> o1/l1 plain stores; k_norm combines.
// P software-pipelined one tile (ping-pong parity buffers), no in-loop
// lgkmcnt(0). Cooperative double-buffered K/V LDS staging, 1 barrier/iter.
__global__ __launch_bounds__(128, 2) void k_attn(const bf16_t* __restrict__ qb,
                                                 const bf16_t* __restrict__ kb,
                                                 const bf16_t* __restrict__ vt,
                                                 bf16_t* __restrict__ yb,
                                                 float* __restrict__ o0,
                                                 float* __restrict__ o1,
                                                 float* __restrict__ l0,
                                                 float* __restrict__ l1) {
    __shared__ bf16_t Kb[2][32 * 72];      // key row stride 144B
    __shared__ bf16_t Vb[2][64 * 40];      // d row stride 80B
    __shared__ bf16_t Ps[2][2][32 * PST2]; // [wave][parity]
    const int tid = threadIdx.x;
    const int w = tid >> 6, lane = tid & 63;
    const int quad = lane >> 4, lrow = lane & 15;
    const int bh = blockIdx.x & 31;
    const int j = blockIdx.x >> 5;                 // 0..47
    const int qg = ORD[j][0];
    const int cc = ORD[j][1];                      // -1 = unsplit
    const int ct = (cc < 0) ? (2 * qg + 2) : (qg + 1);
    const int key0 = (cc == 1) ? (qg + 1) * 32 : 0;
    const int kendl = 2 * qg + w + 1 - ((cc == 1) ? (qg + 1) : 0);
    const int kw = min(kendl, ct);
    const int q0 = qg * 64 + w * 32;

    const bf16_t* Qg = qb + (size_t)bh * TT * HS;
    const bf16_t* Kg = kb + (size_t)bh * TT * HS;
    const bf16_t* Vg = vt + (size_t)bh * HS * TT;

    const int skey = tid >> 2, scol = (tid & 3) * 16;
    const int svrow = tid >> 1, svcol = (tid & 1) * 16;

    bf16x8 kra, krb, vra, vrb;
    {   // prestage tile 0
        const bf16_t* gk = Kg + (size_t)(key0 + skey) * HS + scol;
        kra = *(const bf16x8*)(gk);
        krb = *(const bf16x8*)(gk + 8);
        const bf16_t* gv = Vg + (size_t)svrow * TT + key0 + svcol;
        vra = *(const bf16x8*)(gv);
        vrb = *(const bf16x8*)(gv + 8);
        *(bf16x8*)(&Kb[0][skey * 72 + scol])     = kra;
        *(bf16x8*)(&Kb[0][skey * 72 + scol + 8]) = krb;
        *(bf16x8*)(&Vb[0][svrow * 40 + svcol])     = vra;
        *(bf16x8*)(&Vb[0][svrow * 40 + svcol + 8]) = vrb;
    }

    bf16x8 aq[2][2];
    for (int tq = 0; tq < 2; ++tq)
        for (int c = 0; c < 2; ++c)
            aq[tq][c] = *(const bf16x8*)(Qg + (size_t)(q0 + tq * 16 + lrow) * HS + c * 32 + quad * 8);

    const bf16_t onebf = __builtin_bit_cast(bf16_t, (unsigned short)0x3F80);
    bf16x8 bones = {onebf, onebf, onebf, onebf, onebf, onebf, onebf, onebf};

    floatx4 o[2][4];
    for (int tq = 0; tq < 2; ++tq)
        for (int dc = 0; dc < 4; ++dc) o[tq][dc] = floatx4{0.f, 0.f, 0.f, 0.f};
    floatx4 ol[2] = {floatx4{0.f,0.f,0.f,0.f}, floatx4{0.f,0.f,0.f,0.f}};

    bf16x8 bv_sav[4];
    const int wrow0 = quad * 4;

    for (int t = 0; t < ct; ++t) {
        __syncthreads();   // staging writes of t (done at end of t-1) visible
        if (t + 1 < ct) {  // post-barrier prefetch of next tile into regs
            const bf16_t* gk = Kg + (size_t)(key0 + (t + 1) * 32 + skey) * HS + scol;
            kra = *(const bf16x8*)(gk);
            krb = *(const bf16x8*)(gk + 8);
            const bf16_t* gv = Vg + (size_t)svrow * TT + key0 + (t + 1) * 32 + svcol;
            vra = *(const bf16x8*)(gv);
            vrb = *(const bf16x8*)(gv + 8);
        }
        if (t < kw) {
            // ---- deferred PV for tile t-1 (P from parity buffer, V from regs)
            if (t > 0) {
                const bf16_t* Pp = &Ps[w][(t - 1) & 1][0];
                bf16x8 pa0 = *(const bf16x8*)(Pp + (size_t)lrow * PST2 + quad * 8);
                bf16x8 pa1 = *(const bf16x8*)(Pp + (size_t)(16 + lrow) * PST2 + quad * 8);
                o[0][0] = __builtin_amdgcn_mfma_f32_16x16x32_bf16(pa0, bv_sav[0], o[0][0], 0, 0, 0);
                o[0][1] = __builtin_amdgcn_mfma_f32_16x16x32_bf16(pa0, bv_sav[1], o[0][1], 0, 0, 0);
                o[0][2] = __builtin_amdgcn_mfma_f32_16x16x32_bf16(pa0, bv_sav[2], o[0][2], 0, 0, 0);
                o[0][3] = __builtin_amdgcn_mfma_f32_16x16x32_bf16(pa0, bv_sav[3], o[0][3], 0, 0, 0);
                ol[0]   = __builtin_amdgcn_mfma_f32_16x16x32_bf16(pa0, bones, ol[0], 0, 0, 0);
                o[1][0] = __builtin_amdgcn_mfma_f32_16x16x32_bf16(pa1, bv_sav[0], o[1][0], 0, 0, 0);
                o[1][1] = __builtin_amdgcn_mfma_f32_16x16x32_bf16(pa1, bv_sav[1], o[1][1], 0, 0, 0);
                o[1][2] = __builtin_amdgcn_mfma_f32_16x16x32_bf16(pa1, bv_sav[2], o[1][2], 0, 0, 0);
                o[1][3] = __builtin_amdgcn_mfma_f32_16x16x32_bf16(pa1, bv_sav[3], o[1][3], 0, 0, 0);
                ol[1]   = __builtin_amdgcn_mfma_f32_16x16x32_bf16(pa1, bones, ol[1], 0, 0, 0);
            }
            // ---- QK^T for tile t
            const bf16_t* Kt = &Kb[t & 1][0];
            const bf16_t* Vt = &Vb[t & 1][0];
            bf16x8 bk0 = *(const bf16x8*)(Kt + lrow * 72 + quad * 8);
            bf16x8 bk1 = *(const bf16x8*)(Kt + lrow * 72 + 32 + quad * 8);
            bf16x8 bk2 = *(const bf16x8*)(Kt + (16 + lrow) * 72 + quad * 8);
            bf16x8 bk3 = *(const bf16x8*)(Kt + (16 + lrow) * 72 + 32 + quad * 8);
            floatx4 s00 = floatx4{0.f,0.f,0.f,0.f}, s01 = s00, s10 = s00, s11 = s00;
            s00 = __builtin_amdgcn_mfma_f32_16x16x32_bf16(aq[0][0], bk0, s00, 0, 0, 0);
            s00 = __builtin_amdgcn_mfma_f32_16x16x32_bf16(aq[0][1], bk1, s00, 0, 0, 0);
            s01 = __builtin_amdgcn_mfma_f32_16x16x32_bf16(aq[0][0], bk2, s01, 0, 0, 0);
            s01 = __builtin_amdgcn_mfma_f32_16x16x32_bf16(aq[0][1], bk3, s01, 0, 0, 0);
            s10 = __builtin_amdgcn_mfma_f32_16x16x32_bf16(aq[1][0], bk0, s10, 0, 0, 0);
            s10 = __builtin_amdgcn_mfma_f32_16x16x32_bf16(aq[1][1], bk1, s10, 0, 0, 0);
            s11 = __builtin_amdgcn_mfma_f32_16x16x32_bf16(aq[1][0], bk2, s11, 0, 0, 0);
            s11 = __builtin_amdgcn_mfma_f32_16x16x32_bf16(aq[1][1], bk3, s11, 0, 0, 0);

            bv_sav[0] = *(const bf16x8*)(Vt + (0  + lrow) * 40 + quad * 8);
            bv_sav[1] = *(const bf16x8*)(Vt + (16 + lrow) * 40 + quad * 8);
            bv_sav[2] = *(const bf16x8*)(Vt + (32 + lrow) * 40 + quad * 8);
            bv_sav[3] = *(const bf16x8*)(Vt + (48 + lrow) * 40 + quad * 8);

            uint32_t* P32 = (uint32_t*)(&Ps[w][t & 1][0]);
            if (t < kendl - 1) {            // unmasked tile
                for (int r = 0; r < 4; ++r) {
                    float e00 = __builtin_amdgcn_exp2f(s00[r]);
                    float e01 = __builtin_amdgcn_exp2f(s01[r]);
                    float e10 = __builtin_amdgcn_exp2f(s10[r]);
                    float e11 = __builtin_amdgcn_exp2f(s11[r]);
                    uint32_t pk0 = __builtin_amdgcn_perm(
                        __builtin_bit_cast(uint32_t, e01),
                        __builtin_bit_cast(uint32_t, e00), 0x07060302u);
                    uint32_t pk1 = __builtin_amdgcn_perm(
                        __builtin_bit_cast(uint32_t, e11),
                        __builtin_bit_cast(uint32_t, e10), 0x07060302u);
                    P32[(wrow0 + r) * 20 + lrow]      = pk0;
                    P32[(wrow0 + r + 16) * 20 + lrow] = pk1;
                }
            } else {                        // diagonal tile (keys start at q0)
                for (int r = 0; r < 4; ++r) {
                    bool keep = lrow <= quad * 4 + r;
                    float e00 = keep ? __builtin_amdgcn_exp2f(s00[r]) : 0.f;
                    float e01 = 0.f; (void)s01;
                    float e10 = __builtin_amdgcn_exp2f(s10[r]);
                    float e11 = keep ? __builtin_amdgcn_exp2f(s11[r]) : 0.f;
                    uint32_t pk0 = __builtin_amdgcn_perm(
                        __builtin_bit_cast(uint32_t, e01),
                        __builtin_bit_cast(uint32_t, e00), 0x07060302u);
                    uint32_t pk1 = __builtin_amdgcn_perm(
                        __builtin_bit_cast(uint32_t, e11),
                        __builtin_bit_cast(uint32_t, e10), 0x07060302u);
                    P32[(wrow0 + r) * 20 + lrow]      = pk0;
                    P32[(wrow0 + r + 16) * 20 + lrow] = pk1;
                }
            }
        }
        if (t + 1 < ct) {   // write staged K/V into the other buffer
            bf16_t* Kn = &Kb[(t + 1) & 1][0];
            bf16_t* Vn = &Vb[(t + 1) & 1][0];
            *(bf16x8*)(Kn + skey * 72 + scol)     = kra;
            *(bf16x8*)(Kn + skey * 72 + scol + 8) = krb;
            *(bf16x8*)(Vn + svrow * 40 + svcol)     = vra;
            *(bf16x8*)(Vn + svrow * 40 + svcol + 8) = vrb;
        }
    }

    // ---- final deferred PV (tile kw-1)
    asm volatile("s_waitcnt lgkmcnt(0)" ::: "memory");
    {
        const bf16_t* Pp = &Ps[w][(kw - 1) & 1][0];
        bf16x8 pa0 = *(const bf16x8*)(Pp + (size_t)lrow * PST2 + quad * 8);
        bf16x8 pa1 = *(const bf16x8*)(Pp + (size_t)(16 + lrow) * PST2 + quad * 8);
        o[0][0] = __builtin_amdgcn_mfma_f32_16x16x32_bf16(pa0, bv_sav[0], o[0][0], 0, 0, 0);
        o[0][1] = __builtin_amdgcn_mfma_f32_16x16x32_bf16(pa0, bv_sav[1], o[0][1], 0, 0, 0);
        o[0][2] = __builtin_amdgcn_mfma_f32_16x16x32_bf16(pa0, bv_sav[2], o[0][2], 0, 0, 0);
        o[0][3] = __builtin_amdgcn_mfma_f32_16x16x32_bf16(pa0, bv_sav[3], o[0][3], 0, 0, 0);
        ol[0]   = __builtin_amdgcn_mfma_f32_16x16x32_bf16(pa0, bones, ol[0], 0, 0, 0);
        o[1][0] = __builtin_amdgcn_mfma_f32_16x16x32_bf16(pa1, bv_sav[0], o[1][0], 0, 0, 0);
        o[1][1] = __builtin_amdgcn_mfma_f32_16x16x32_bf16(pa1, bv_sav[1], o[1][1], 0, 0, 0);
        o[1][2] = __builtin_amdgcn_mfma_f32_16x16x32_bf16(pa1, bv_sav[2], o[1][2], 0, 0, 0);
        o[1][3] = __builtin_amdgcn_mfma_f32_16x16x32_bf16(pa1, bv_sav[3], o[1][3], 0, 0, 0);
        ol[1]   = __builtin_amdgcn_mfma_f32_16x16x32_bf16(pa1, bones, ol[1], 0, 0, 0);
    }

    // ---- epilogue
    if (cc < 0) {           // unsplit: normalize locally, write yb directly
        const int b = bh >> 4, h = bh & 15;
        for (int tq = 0; tq < 2; ++tq)
            for (int r = 0; r < 4; ++r) {
                float inv = 1.0f / ol[tq][r];
                int q = q0 + tq * 16 + quad * 4 + r;
                for (int dc = 0; dc < 4; ++dc)
                    yb[(size_t)(b * TT + q) * CC + h * HS + dc * 16 + lrow] =
                        f2bf(o[tq][dc][r] * inv);
            }
    } else if (cc == 1) {   // split back half
        for (int tq = 0; tq < 2; ++tq)
            for (int r = 0; r < 4; ++r) {
                int q = q0 + tq * 16 + quad * 4 + r;
                float* dst = o1 + ((size_t)(bh * 16 + qg - 16) * 64 + (q - qg * 64)) * 64 + lrow;
                for (int dc = 0; dc < 4; ++dc) dst[dc * 16] = o[tq][dc][r];
                if (lrow == 0) l1[(size_t)(bh * 16 + qg - 16) * 64 + (q - qg * 64)] = ol[tq][r];
            }
    } else {                // split front half
        for (int tq = 0; tq < 2; ++tq)
            for (int r = 0; r < 4; ++r) {
                int q = q0 + tq * 16 + quad * 4 + r;
                float* dst = o0 + ((size_t)bh * TT + q) * HS + lrow;
                for (int dc = 0; dc < 4; ++dc) dst[dc * 16] = o[tq][dc][r];
                if (lrow == 0) l0[(size_t)bh * TT + q] = ol[tq][r];
            }
    }
}

// ---------------------------------------------------------------- normalize + combine (split rows only, q>=1024)
__global__ __launch_bounds__(256) void k_norm(const float* __restrict__ o0,
                                              const float* __restrict__ o1,
                                              const float* __restrict__ l0,
                                              const float* __restrict__ l1,
                                              bf16_t* __restrict__ yb) {
    int idx = blockIdx.x * 256 + threadIdx.x;      // over 32 bh x 1024 q x 8
    int d8 = idx & 7;
    int q  = 1024 + ((idx >> 3) & 1023);
    int bh = idx >> 13;
    int qg = q >> 6;
    const float* s0 = o0 + ((size_t)bh * TT + q) * HS + d8 * 8;
    const float* s1 = o1 + ((size_t)(bh * 16 + qg - 16) * 64 + (q & 63)) * 64 + d8 * 8;
    float4 a = *(const float4*)(s0);
    float4 b = *(const float4*)(s0 + 4);
    float4 a1 = *(const float4*)(s1);
    float4 b1 = *(const float4*)(s1 + 4);
    a.x += a1.x; a.y += a1.y; a.z += a1.z; a.w += a1.w;
    b.x += b1.x; b.y += b1.y; b.z += b1.z; b.w += b1.w;
    float l = l0[(size_t)bh * TT + q] + l1[(size_t)(bh * 16 + qg - 16) * 64 + (q & 63)];
    float inv = 1.0f / l;
    bf16x8 r;
    r[0] = f2bf(a.x * inv); r[1] = f2bf(a.y * inv);
    r[2] = f2bf(a.z * inv); r[3] = f2bf(a.w * inv);
    r[4] = f2bf(b.x * inv); r[5] = f2bf(b.y * inv);
    r[6] = f2bf(b.z * inv); r[7] = f2bf(b.w * inv);
    int bb = bh >> 4, h = bh & 15;
    *(bf16x8*)(yb + ((size_t)(bb * TT + q)) * CC + h * HS + d8 * 8) = r;
}

// ---------------------------------------------------------------- out GEMM (fp32 out + bias)
// r4 ring structure ported (r6-verified win): 128x64 tile, 256 threads, 4-slot
// LDS ring (48 KB -> 3 blocks/CU), counted vmcnt(6), pre-swizzled source +
// swizzled ds_read, setprio. 512 blocks + bijective XCD swizzle.
__global__ __launch_bounds__(256, 2) void k_gemm_out(const bf16_t* __restrict__ yin,
                                                     const bf16_t* __restrict__ Wt,
                                                     const float* __restrict__ bias,
                                                     float* __restrict__ out) {
    __shared__ bf16_t As[4][128 * 32];   // 8 KB/slot
    __shared__ bf16_t Bs[4][64 * 32];    // 4 KB/slot -> 48 KB total
    const int tid = threadIdx.x;
    const int wave = tid >> 6, lane = tid & 63;
    const int quad = lane >> 4, lrow = lane & 15;
    const int wm = wave >> 1, wn = wave & 1;         // 2x2 wave grid, 64x32/wave

    const int bid = blockIdx.y * 16 + blockIdx.x;
    const int swz = (bid & 7) * 64 + (bid >> 3);     // 64 contiguous tiles/XCD
    const int m0 = (swz >> 4) * 128, n0 = (swz & 15) * 64;

    floatx4 acc[4][2];
    #pragma unroll
    for (int i = 0; i < 4; ++i)
        #pragma unroll
        for (int j = 0; j < 2; ++j) acc[i][j] = floatx4{0.f, 0.f, 0.f, 0.f};

    // per K-tile: A = 512 chunks (2/thread), B = 256 chunks (1/thread) -> 3
    // uniform loads/thread. Pre-swizzled source gc = cs ^ ((row>>1)&3).
    auto stage = [&](int kt) {
        const int slot = kt & 3;
        const int kk = kt * 32;
        #pragma unroll
        for (int l = 0; l < 2; ++l) {
            int L = l * 256 + tid;
            int row = L >> 2, cs = L & 3;
            int gc = cs ^ ((row >> 1) & 3);
            load_lds16(yin + (size_t)(m0 + row) * CC + kk + gc * 8,
                       &As[slot][(size_t)(l * 256 + wave * 64) * 8]);
        }
        {
            int row = tid >> 2, cs = tid & 3;
            int gc = cs ^ ((row >> 1) & 3);
            load_lds16(Wt + (size_t)(n0 + row) * CC + kk + gc * 8,
                       &Bs[slot][(size_t)(wave * 64) * 8]);
        }
    };

    const int csw = (quad ^ ((lrow >> 1) & 3)) * 8;

    auto do_tile = [&](int kt, bool st) {
        const bf16_t* Ab = &As[kt & 3][0];
        const bf16_t* Bb = &Bs[kt & 3][0];
        bf16x8 af[4], bfr[2];
        #pragma unroll
        for (int i = 0; i < 4; ++i)
            af[i] = *(const bf16x8*)(Ab + (wm * 64 + i * 16 + lrow) * 32 + csw);
        #pragma unroll
        for (int j = 0; j < 2; ++j)
            bfr[j] = *(const bf16x8*)(Bb + (wn * 32 + j * 16 + lrow) * 32 + csw);
        if (st) stage(kt + 3);
        __builtin_amdgcn_s_barrier();
        __builtin_amdgcn_s_setprio(1);
        #pragma unroll
        for (int i = 0; i < 4; ++i)
            #pragma unroll
            for (int j = 0; j < 2; ++j)
                acc[i][j] = __builtin_amdgcn_mfma_f32_16x16x32_bf16(af[i], bfr[j], acc[i][j], 0, 0, 0);
        __builtin_amdgcn_s_setprio(0);
    };

    // prologue: 3 tiles in flight (9 loads/thread); tile0 ready at vmcnt(6)
    stage(0); stage(1); stage(2);
    asm volatile("s_waitcnt vmcnt(6)" ::: "memory");
    __builtin_amdgcn_s_barrier();

    for (int kt = 0; kt < 29; ++kt) {
        do_tile(kt, true);
        asm volatile("s_waitcnt vmcnt(6)" ::: "memory");
        __builtin_amdgcn_s_barrier();
    }
    // drain 6 -> 3 -> 0
    do_tile(29, false);
    asm volatile("s_waitcnt vmcnt(3)" ::: "memory");
    __builtin_amdgcn_s_barrier();
    do_tile(30, false);
    asm volatile("s_waitcnt vmcnt(0)" ::: "memory");
    __builtin_amdgcn_s_barrier();
    do_tile(31, false);

    #pragma unroll
    for (int i = 0; i < 4; ++i)
        #pragma unroll
        for (int j = 0; j < 2; ++j) {
            int gn = n0 + wn * 32 + j * 16 + lrow;
            float bb = bias[gn];
            #pragma unroll
            for (int r = 0; r < 4; ++r) {
                int gm = m0 + wm * 64 + i * 16 + quad * 4 + r;
                out[(size_t)gm * CC + gn] = acc[i][j][r] + bb;
            }
        }
}

// ---------------------------------------------------------------- launch
extern "C" void kernel_launch(void* const* d_in, const int* in_sizes, int n_in,
                              void* d_out, int out_size, void* d_ws, size_t ws_size,
                              hipStream_t stream) {
    (void)in_sizes; (void)n_in; (void)out_size; (void)ws_size;
    const float* x    = (const float*)d_in[0];  // [2,2048,1024] fp32
    const float* Wqkv = (const float*)d_in[1];  // [1024,3072]   fp32
    const float* Wout = (const float*)d_in[2];  // [1024,1024]   fp32
    const float* bout = (const float*)d_in[3];  // [1024]        fp32
    float* out = (float*)d_out;                 // [2,2048,1024] fp32

    bf16_t* xb  = (bf16_t*)d_ws;                        // [4096][1024]  8 MB
    bf16_t* Wt1 = xb + (size_t)MM * CC;                 // [3072][1024]  6 MB
    bf16_t* Wt2 = Wt1 + (size_t)N1 * CC;                // [1024][1024]  2 MB
    bf16_t* qb  = Wt2 + (size_t)CC * CC;                // [B,H,T,hs]    8 MB
    bf16_t* kb  = qb + (size_t)BB * HH * TT * HS;       // [B,H,T,hs]    8 MB
    bf16_t* vb  = kb + (size_t)BB * HH * TT * HS;       // [B,H,hs,T~]   8 MB (perm)
    bf16_t* yb  = vb + (size_t)BB * HH * TT * HS;       // [B,T,C] bf16  8 MB
    float*  o0  = (float*)d_out; // 16 MB partial-0; dead before k_gemm_out writes
    float*  o1  = (float*)xb;    // 8 MB partial-1; xb dead after k_gemm_qkv
    float*  l0  = (float*)Wt1;   // 256 KB; Wt1 dead after k_gemm_qkv
    float*  l1  = l0 + (size_t)BB * HH * TT;            // 128 KB

    k_prep<<<dim3(2048 + 3072 + 1024), 256, 0, stream>>>(x, Wqkv, Wout, xb, Wt1, Wt2);
    k_gemm_qkv<<<dim3(16, 16), 512, 0, stream>>>(xb, Wt1, qb, kb, vb);
    k_attn<<<dim3(48 * 32), 128, 0, stream>>>(qb, kb, vb, yb, o0, o1, l0, l1);
    k_norm<<<dim3(1024), 256, 0, stream>>>(o0, o1, l0, l1, yb);
    k_gemm_out<<<dim3(CC / 64, MM / 128), 256, 0, stream>>>(yb, Wt2, bout, out);
}